// Round 9
// baseline (710.361 us; speedup 1.0000x reference)
//
#include <hip/hip_runtime.h>
#include <hip/hip_bf16.h>
#include <math.h>

#define LDIM 4096
#define PDIM 4098   // 1-elem reflect pad each side
#define EPSF 1e-9f

using f32x4  = __attribute__((ext_vector_type(4))) float;
using short8 = __attribute__((ext_vector_type(8))) short;

#define AS1 __attribute__((address_space(1)))
#define AS3 __attribute__((address_space(3)))

__device__ __forceinline__ void gload_lds16(const void* g, void* l) {
    __builtin_amdgcn_global_load_lds((const AS1 unsigned int*)g,
                                     (AS3 unsigned int*)l, 16, 0, 0);
}

__device__ __forceinline__ float bf2f(unsigned short u) {
    unsigned int b = ((unsigned int)u) << 16;
    return __builtin_bit_cast(float, b);
}

// ---------------- sp = (s*mask).sum(-1)/len  ----------------
__global__ void sp_kernel(const float* __restrict__ s, const int* __restrict__ lengths,
                          float* __restrict__ sp) {
    int b = blockIdx.x >> 7;
    int d = blockIdx.x & 127;
    int len = lengths[b];
    const float* row = s + ((size_t)(b * 128 + d)) * LDIM;
    float acc = 0.f;
    int len4 = len & ~3;
    for (int l = threadIdx.x * 4; l < len4; l += 1024) {
        f32x4 v = *(const f32x4*)(row + l);
        acc += v[0] + v[1] + v[2] + v[3];
    }
    for (int l = len4 + threadIdx.x; l < len; l += 256) acc += row[l];
    for (int off = 32; off; off >>= 1) acc += __shfl_down(acc, off, 64);
    __shared__ float red[4];
    if ((threadIdx.x & 63) == 0) red[threadIdx.x >> 6] = acc;
    __syncthreads();
    if (threadIdx.x == 0)
        sp[b * 128 + d] = (red[0] + red[1] + red[2] + red[3]) / (float)len;
}

// ---------------- h1 = sp@fc1^T+b1, h2 = sp@fc2^T+b2 ----------------
__global__ void fc_kernel(const float* __restrict__ sp,
                          const float* __restrict__ w1, const float* __restrict__ b1,
                          const float* __restrict__ w2, const float* __restrict__ b2,
                          float* __restrict__ h1, float* __restrict__ h2) {
    int idx = blockIdx.x * 256 + threadIdx.x;   // 16 * 1536
    int b = idx / 1536, j = idx % 1536;
    const float* spb = sp + b * 128;
    if (j < 512) {
        const float* wr = w1 + (size_t)j * 128;
        float acc = b1[j];
        for (int d = 0; d < 128; ++d) acc = fmaf(spb[d], wr[d], acc);
        h1[b * 512 + j] = acc;
    } else {
        int j2 = j - 512;
        const float* wr = w2 + (size_t)j2 * 128;
        float acc = b2[j2];
        for (int d = 0; d < 128; ++d) acc = fmaf(spb[d], wr[d], acc);
        h2[b * 1024 + j2] = acc;
    }
}

// ---------------- AdaWin + LReLU: in [b][C][L] -> out bf16 transposed [b][PDIM][C] ----------------
// Vectorized loads (float4 / short8) over aligned span [l0-64, l0+320); all xs
// indices shifted +28 vs the proven base-36 version. Math identical.
// XOUT: also emit bf16 of the raw input, transposed+padded (fused xcvt).
template<bool XOUT, typename TIN>
__global__ __launch_bounds__(256) void adawin_t_kernel(const TIN* __restrict__ in,
        const float* __restrict__ h, const int* __restrict__ lengths,
        __hip_bfloat16* __restrict__ out, __hip_bfloat16* __restrict__ xout, int C) {
    __shared__ float xs[16][384];           // raw x then (x-mean)^2*mask; j=0 <-> l0-64
    __shared__ float ms[16][293];           // means, mj=0 <-> l0-18
    __shared__ __hip_bfloat16 os[256][16];  // output staging (transposed)
    int l0 = blockIdx.x * 256, c0 = blockIdx.y * 16, b = blockIdx.z;
    int tid = threadIdx.x;
    int c = tid >> 4, sub = tid & 15;
    int len = lengths[b];

    if constexpr (sizeof(TIN) == 4) {       // f32 input: 96 float4 per row
        for (int i = 0; i < 6; ++i) {
            int idx = tid + i * 256;
            int r = idx / 96, j4 = idx % 96;
            int l = l0 - 64 + j4 * 4;
            f32x4 v = {};
            if (l >= 0 && l < LDIM)
                v = *(const f32x4*)((const float*)in + ((size_t)b * C + c0 + r) * LDIM + l);
            *(f32x4*)&xs[r][j4 * 4] = v;
        }
    } else {                                // bf16 input: 48 short8 per row
        for (int i = 0; i < 3; ++i) {
            int idx = tid + i * 256;
            int r = idx / 48, j8 = idx % 48;
            int l = l0 - 64 + j8 * 8;
            float f[8] = {};
            if (l >= 0 && l < LDIM) {
                short8 v = *(const short8*)((const __hip_bfloat16*)in +
                                            ((size_t)b * C + c0 + r) * LDIM + l);
                #pragma unroll
                for (int k = 0; k < 8; ++k) f[k] = bf2f((unsigned short)v[k]);
            }
            #pragma unroll
            for (int k = 0; k < 8; ++k) xs[r][j8 * 8 + k] = f[k];
        }
    }
    __syncthreads();

    if constexpr (XOUT) {     // fused x -> bf16 transposed (xs still raw here)
        for (int idx = tid; idx < 512; idx += 256) {
            int row = idx >> 1, hh = idx & 1;
            short8 v;
            #pragma unroll
            for (int k = 0; k < 8; ++k) {
                __hip_bfloat16 t = __float2bfloat16(xs[hh * 8 + k][row + 64]);
                v[k] = *(short*)&t;
            }
            *(short8*)&xout[((size_t)b * PDIM + l0 + row + 1) * 256 + c0 + hh * 8] = v;
            if (l0 == 0 && row == 1)
                *(short8*)&xout[((size_t)b * PDIM) * 256 + c0 + hh * 8] = v;
            if (l0 == LDIM - 256 && row == 254)
                *(short8*)&xout[((size_t)b * PDIM + LDIM + 1) * 256 + c0 + hh * 8] = v;
        }
    }

    // means for mj in [0,292): l = l0-18+mj; numerator unmasked, denom masked
    int mstart = sub * 19;
    int mend = min(mstart + 19, 292);
    float S = 0.f;
    for (int k = 0; k <= 36; ++k) S += xs[c][mstart + k + 28];
    for (int mj = mstart; mj < mend; ++mj) {
        if (mj > mstart) S += xs[c][mj + 64] - xs[c][mj + 27];
        int l = l0 - 18 + mj;
        int lo = max(l - 18, 0), hi = min(l + 19, len);
        float den = (float)(hi - lo) + EPSF;
        ms[c][mj] = (l >= 0 && l < len) ? S / den : 0.f;
    }
    __syncthreads();

    float dwn[16];
    int lbase = l0 + sub * 16;
    #pragma unroll
    for (int t = 0; t < 16; ++t)
        dwn[t] = xs[c][sub * 16 + t + 64] - ms[c][sub * 16 + t + 18];
    __syncthreads();

    // sq in place over xs
    for (int mj = mstart; mj < mend; ++mj) {
        int l = l0 - 18 + mj;
        float d = xs[c][mj + 46] - ms[c][mj];
        xs[c][mj + 46] = (l >= 0 && l < len) ? d * d : 0.f;
    }
    __syncthreads();

    float gamma = h[(size_t)b * 2 * C + c0 + c];
    float beta  = h[(size_t)b * 2 * C + C + c0 + c];
    float S2 = 0.f;
    for (int k = 0; k <= 36; ++k) S2 += xs[c][sub * 16 + 46 + k];
    #pragma unroll
    for (int t = 0; t < 16; ++t) {
        int l = lbase + t;
        if (t) S2 += xs[c][sub * 16 + t + 82] - xs[c][sub * 16 + t + 45];
        int lo = max(l - 18, 0), hi = min(l + 19, len);
        float den = (float)(hi - lo) + EPSF;
        float var = (l < len) ? S2 / den : 0.f;
        float xn = dwn[t] * rsqrtf(var + EPSF);
        float v = fmaf(gamma, xn, xn) + beta;
        v = v > 0.f ? v : 0.2f * v;
        os[sub * 16 + t][c] = __float2bfloat16(v);
    }
    __syncthreads();

    for (int idx = tid; idx < 512; idx += 256) {
        int row = idx >> 1, hh = idx & 1;
        short8 v = *(const short8*)&os[row][hh * 8];
        *(short8*)&out[((size_t)b * PDIM + l0 + row + 1) * C + c0 + hh * 8] = v;
        if (l0 == 0 && row == 1)
            *(short8*)&out[((size_t)b * PDIM) * C + c0 + hh * 8] = v;
        if (l0 == LDIM - 256 && row == 254)
            *(short8*)&out[((size_t)b * PDIM + LDIM + 1) * C + c0 + hh * 8] = v;
    }
}

// ---------------- weight prep ----------------
// [O][I][3] f32 -> [O][3][I] bf16
__global__ void wp3_kernel(const float* __restrict__ in, __hip_bfloat16* __restrict__ o,
                           int I, int total) {
    int idx = blockIdx.x * 256 + threadIdx.x;
    if (idx >= total) return;
    int t = idx % 3;
    int rest = idx / 3;
    int i = rest % I;
    int oo = rest / I;
    o[((size_t)oo * 3 + t) * I + i] = __float2bfloat16(in[idx]);
}

__global__ void wcvt_kernel(const float* __restrict__ in, __hip_bfloat16* __restrict__ o, int total) {
    int idx = blockIdx.x * 256 + threadIdx.x;
    if (idx < total) o[idx] = __float2bfloat16(in[idx]);
}

// ---------------- conv1d(k=3, reflect) as MFMA implicit GEMM ----------------
// BK=64 round-3/5 LDS layout (proven 0-conflict 8-slot XOR involution).
// KEY CHANGE (round 9): all 24 chunk weights are loaded into a SINGLE register
// bank BEFORE the stage issue (one sched_barrier pins that boundary). Weight
// consume-waits (oldest vmem ops) then never transitively drain the stage
// (vmcnt retires in order); the only stage drain is the barrier's vmcnt(0),
// which now has the whole 96-MFMA + 24-ds_read compute region covering it --
// the m97-equivalent schedule. Single bank = ~200 VGPR, cap 256 via
// __launch_bounds__(256,2) -> no spill (round-6 lesson: 2 banks spill).
template<int CIN, bool SC, bool FINAL, typename TOUT>
__global__ __launch_bounds__(256, 2) void conv_mfma_kernel(
    const __hip_bfloat16* __restrict__ act,
    const __hip_bfloat16* __restrict__ wt,
    const float* __restrict__ bias,
    const __hip_bfloat16* __restrict__ xsc,
    const __hip_bfloat16* __restrict__ wsc,
    TOUT* __restrict__ out)
{
    constexpr int NCM = CIN / 64;                 // main K-chunks (64 ch each)
    constexpr int NCT = NCM + (SC ? 4 : 0);       // + shortcut chunks
    __shared__ alignas(16) char lds[2][16640];    // 130 rows x 128B, double buffered
    int tid = threadIdx.x;
    int lane = tid & 63;
    int w = tid >> 6, wm = w >> 1, wn = w & 1;    // 2x2 wave grid, 64x64 per wave
    int l0 = blockIdx.x * 128, o0 = blockIdx.y * 128, b = blockIdx.z;

    f32x4 acc[4][4] = {};

    auto stage = [&](int kc, char* buf) {
        const __hip_bfloat16* src;
        int cs, cb;
        if (!SC || kc < NCM) { src = act + (size_t)b * PDIM * CIN; cs = CIN; cb = kc * 64; }
        else                 { src = xsc + (size_t)b * PDIM * 256; cs = 256; cb = (kc - NCM) * 64; }
        // rows p = l0 + 0..129 (l-space l0-1..l0+128), 128B/row = 8 x 16B slots.
        // Linear LDS dest; source slot pre-XORed so the swizzled READ sees the
        // right data (both-sides involution).
        for (int u = tid; u < 1040; u += 256) {
            int row = u >> 3, s = u & 7;
            int gs = s ^ (row & 7);
            const void* g = src + (size_t)(l0 + row) * cs + cb + gs * 8;
            void* d = &buf[(size_t)(u - lane) * 16];   // wave-uniform base; lane adds 16B
            gload_lds16(g, d);
        }
    };

    stage(0, lds[0]);
    __syncthreads();

    int il = lane & 15, g = lane >> 4;

    for (int kc = 0; kc < NCT; ++kc) {
        char* cur = lds[kc & 1];
        bool isSC = SC && (kc >= NCM);

        // ---- weight loads FIRST (single bank, static indices) ----
        short8 af[24];
        if (!isSC) {
            int cb = kc * 64;
            #pragma unroll
            for (int t = 0; t < 3; ++t)
                #pragma unroll
                for (int ks = 0; ks < 2; ++ks) {
                    const __hip_bfloat16* wb = wt + ((size_t)(o0 + wm * 64 + il) * 3 + t) * CIN
                                             + cb + ks * 32 + g * 8;
                    #pragma unroll
                    for (int mm = 0; mm < 4; ++mm)
                        af[(t * 2 + ks) * 4 + mm] = *(const short8*)(wb + (size_t)mm * 16 * 3 * CIN);
                }
        } else {
            int cb = (kc - NCM) * 64;
            #pragma unroll
            for (int ks = 0; ks < 2; ++ks) {
                const __hip_bfloat16* wb = wsc + (size_t)(o0 + wm * 64 + il) * 256
                                         + cb + ks * 32 + g * 8;
                #pragma unroll
                for (int mm = 0; mm < 4; ++mm)
                    af[ks * 4 + mm] = *(const short8*)(wb + (size_t)mm * 16 * 256);
            }
        }
        __builtin_amdgcn_sched_barrier(0);        // pin: stage must not move above weights

        if (kc + 1 < NCT) stage(kc + 1, lds[(kc + 1) & 1]);

        // ---- pure LDS + MFMA region (no global consumes that drain stage) ----
        if (!isSC) {
            #pragma unroll
            for (int t = 0; t < 3; ++t)
                #pragma unroll
                for (int ks = 0; ks < 2; ++ks) {
                    short8 bfr[4];
                    #pragma unroll
                    for (int nn = 0; nn < 4; ++nn) {
                        int row = wn * 64 + nn * 16 + il + t;      // tap shift = LDS row shift
                        int slot = (ks * 4 + g) ^ (row & 7);       // read-side XOR
                        bfr[nn] = *(const short8*)(cur + row * 128 + slot * 16);
                    }
                    #pragma unroll
                    for (int mm = 0; mm < 4; ++mm)
                        #pragma unroll
                        for (int nn = 0; nn < 4; ++nn)
                            acc[mm][nn] = __builtin_amdgcn_mfma_f32_16x16x32_bf16(
                                af[(t * 2 + ks) * 4 + mm], bfr[nn], acc[mm][nn], 0, 0, 0);
                }
        } else {
            #pragma unroll
            for (int ks = 0; ks < 2; ++ks) {
                short8 bfr[4];
                #pragma unroll
                for (int nn = 0; nn < 4; ++nn) {
                    int row = wn * 64 + nn * 16 + il + 1;          // 1x1 conv = center tap
                    int slot = (ks * 4 + g) ^ (row & 7);
                    bfr[nn] = *(const short8*)(cur + row * 128 + slot * 16);
                }
                #pragma unroll
                for (int mm = 0; mm < 4; ++mm)
                    #pragma unroll
                    for (int nn = 0; nn < 4; ++nn)
                        acc[mm][nn] = __builtin_amdgcn_mfma_f32_16x16x32_bf16(
                            af[ks * 4 + mm], bfr[nn], acc[mm][nn], 0, 0, 0);
            }
        }
        __syncthreads();                          // single stage-drain per chunk
    }

    const float scale = FINAL ? 0.70710678118654752440f : 1.0f;
    #pragma unroll
    for (int mm = 0; mm < 4; ++mm) {
        #pragma unroll
        for (int j = 0; j < 4; ++j) {
            int row = o0 + wm * 64 + mm * 16 + g * 4 + j;  // C/D: row=(lane>>4)*4+reg
            float bv = bias[row];
            #pragma unroll
            for (int nn = 0; nn < 4; ++nn) {
                int col = l0 + wn * 64 + nn * 16 + il;     // C/D: col=lane&15
                float v = (acc[mm][nn][j] + bv) * scale;
                if constexpr (__is_same(TOUT, float))
                    out[((size_t)b * 512 + row) * LDIM + col] = v;
                else
                    out[((size_t)b * 512 + row) * LDIM + col] = __float2bfloat16(v);
            }
        }
    }
}

extern "C" void kernel_launch(void* const* d_in, const int* in_sizes, int n_in,
                              void* d_out, int out_size, void* d_ws, size_t ws_size,
                              hipStream_t stream) {
    const float* x    = (const float*)d_in[0];
    const float* s    = (const float*)d_in[1];
    const int*   lens = (const int*)d_in[2];
    const float* fc1w = (const float*)d_in[3];
    const float* fc1b = (const float*)d_in[4];
    const float* fc2w = (const float*)d_in[5];
    const float* fc2b = (const float*)d_in[6];
    const float* c1w  = (const float*)d_in[7];
    const float* c1b  = (const float*)d_in[8];
    const float* c2w  = (const float*)d_in[9];
    const float* c2b  = (const float*)d_in[10];
    const float* scw  = (const float*)d_in[11];
    float* out = (float*)d_out;

    char* ws = (char*)d_ws;
    float*          sp  = (float*)(ws);
    float*          h1  = (float*)(ws + ((size_t)1 << 20));
    float*          h2  = (float*)(ws + ((size_t)2 << 20));
    __hip_bfloat16* w1t = (__hip_bfloat16*)(ws + ((size_t)3 << 20));   // 512*768*2  = 768KB
    __hip_bfloat16* w2t = (__hip_bfloat16*)(ws + ((size_t)4 << 20));   // 512*1536*2 = 1.5MB
    __hip_bfloat16* wsc = (__hip_bfloat16*)(ws + ((size_t)6 << 20));   // 512*256*2  = 256KB
    __hip_bfloat16* xbf = (__hip_bfloat16*)(ws + ((size_t)8 << 20));   // 16*4098*256*2 = 33.6MB
    __hip_bfloat16* a1t = (__hip_bfloat16*)(ws + ((size_t)42 << 20));  // 33.6MB
    __hip_bfloat16* a2t = (__hip_bfloat16*)(ws + ((size_t)76 << 20));  // 16*4098*512*2 = 67.1MB
    __hip_bfloat16* y1b = (__hip_bfloat16*)d_out;   // bf16 y1 staged in d_out (fully
                                                    // rewritten f32 by final conv2)

    sp_kernel<<<2048, 256, 0, stream>>>(s, lens, sp);
    fc_kernel<<<96, 256, 0, stream>>>(sp, fc1w, fc1b, fc2w, fc2b, h1, h2);
    wp3_kernel<<<(512 * 256 * 3 + 255) / 256, 256, 0, stream>>>(c1w, w1t, 256, 512 * 256 * 3);
    wp3_kernel<<<(512 * 512 * 3 + 255) / 256, 256, 0, stream>>>(c2w, w2t, 512, 512 * 512 * 3);
    wcvt_kernel<<<512, 256, 0, stream>>>(scw, wsc, 512 * 256);

    adawin_t_kernel<true, float><<<dim3(16, 16, 16), 256, 0, stream>>>(
        x, h1, lens, a1t, xbf, 256);
    conv_mfma_kernel<256, false, false, __hip_bfloat16><<<dim3(32, 4, 16), 256, 0, stream>>>(
        a1t, w1t, c1b, nullptr, nullptr, y1b);
    adawin_t_kernel<false, __hip_bfloat16><<<dim3(16, 32, 16), 256, 0, stream>>>(
        y1b, h2, lens, a2t, nullptr, 512);
    conv_mfma_kernel<512, true, true, float><<<dim3(32, 4, 16), 256, 0, stream>>>(
        a2t, w2t, c2b, xbf, wsc, out);
}

// Round 10
// 605.337 us; speedup vs baseline: 1.1735x; 1.1735x over previous
//
#include <hip/hip_runtime.h>
#include <hip/hip_bf16.h>
#include <math.h>

#define LDIM 4096
#define PDIM 4098   // 1-elem reflect pad each side
#define EPSF 1e-9f

using f32x4  = __attribute__((ext_vector_type(4))) float;
using short8 = __attribute__((ext_vector_type(8))) short;

#define AS1 __attribute__((address_space(1)))
#define AS3 __attribute__((address_space(3)))

__device__ __forceinline__ void gload_lds16(const void* g, void* l) {
    __builtin_amdgcn_global_load_lds((const AS1 unsigned int*)g,
                                     (AS3 unsigned int*)l, 16, 0, 0);
}

__device__ __forceinline__ float bf2f(unsigned short u) {
    unsigned int b = ((unsigned int)u) << 16;
    return __builtin_bit_cast(float, b);
}

// ---------------- sp = (s*mask).sum(-1)/len  ----------------
__global__ void sp_kernel(const float* __restrict__ s, const int* __restrict__ lengths,
                          float* __restrict__ sp) {
    int b = blockIdx.x >> 7;
    int d = blockIdx.x & 127;
    int len = lengths[b];
    const float* row = s + ((size_t)(b * 128 + d)) * LDIM;
    float acc = 0.f;
    int len4 = len & ~3;
    for (int l = threadIdx.x * 4; l < len4; l += 1024) {
        f32x4 v = *(const f32x4*)(row + l);
        acc += v[0] + v[1] + v[2] + v[3];
    }
    for (int l = len4 + threadIdx.x; l < len; l += 256) acc += row[l];
    for (int off = 32; off; off >>= 1) acc += __shfl_down(acc, off, 64);
    __shared__ float red[4];
    if ((threadIdx.x & 63) == 0) red[threadIdx.x >> 6] = acc;
    __syncthreads();
    if (threadIdx.x == 0)
        sp[b * 128 + d] = (red[0] + red[1] + red[2] + red[3]) / (float)len;
}

// ---------------- h1 = sp@fc1^T+b1, h2 = sp@fc2^T+b2 ----------------
__global__ void fc_kernel(const float* __restrict__ sp,
                          const float* __restrict__ w1, const float* __restrict__ b1,
                          const float* __restrict__ w2, const float* __restrict__ b2,
                          float* __restrict__ h1, float* __restrict__ h2) {
    int idx = blockIdx.x * 256 + threadIdx.x;   // 16 * 1536
    int b = idx / 1536, j = idx % 1536;
    const float* spb = sp + b * 128;
    if (j < 512) {
        const float* wr = w1 + (size_t)j * 128;
        float acc = b1[j];
        for (int d = 0; d < 128; ++d) acc = fmaf(spb[d], wr[d], acc);
        h1[b * 512 + j] = acc;
    } else {
        int j2 = j - 512;
        const float* wr = w2 + (size_t)j2 * 128;
        float acc = b2[j2];
        for (int d = 0; d < 128; ++d) acc = fmaf(spb[d], wr[d], acc);
        h2[b * 1024 + j2] = acc;
    }
}

// ---------------- AdaWin + LReLU: in [b][C][L] -> out bf16 transposed [b][PDIM][C] ----------------
// Vectorized loads (float4 / short8) over aligned span [l0-64, l0+320).
// Round-10: IEEE divides (div_scale/fmas/fixup ~10 instrs each) replaced by
// 1-ulp HW approx rcp/rsq -- divisors are window counts (ints 1..37) and
// var+eps; rel err ~2^-22, invisible vs the 3.4x absmax headroom.
// XOUT: also emit bf16 of the raw input, transposed+padded (fused xcvt).
template<bool XOUT, typename TIN>
__global__ __launch_bounds__(256) void adawin_t_kernel(const TIN* __restrict__ in,
        const float* __restrict__ h, const int* __restrict__ lengths,
        __hip_bfloat16* __restrict__ out, __hip_bfloat16* __restrict__ xout, int C) {
    __shared__ float xs[16][384];           // raw x then (x-mean)^2*mask; j=0 <-> l0-64
    __shared__ float ms[16][293];           // means, mj=0 <-> l0-18
    __shared__ __hip_bfloat16 os[256][16];  // output staging (transposed)
    int l0 = blockIdx.x * 256, c0 = blockIdx.y * 16, b = blockIdx.z;
    int tid = threadIdx.x;
    int c = tid >> 4, sub = tid & 15;
    int len = lengths[b];

    if constexpr (sizeof(TIN) == 4) {       // f32 input: 96 float4 per row
        for (int i = 0; i < 6; ++i) {
            int idx = tid + i * 256;
            int r = idx / 96, j4 = idx % 96;
            int l = l0 - 64 + j4 * 4;
            f32x4 v = {};
            if (l >= 0 && l < LDIM)
                v = *(const f32x4*)((const float*)in + ((size_t)b * C + c0 + r) * LDIM + l);
            *(f32x4*)&xs[r][j4 * 4] = v;
        }
    } else {                                // bf16 input: 48 short8 per row
        for (int i = 0; i < 3; ++i) {
            int idx = tid + i * 256;
            int r = idx / 48, j8 = idx % 48;
            int l = l0 - 64 + j8 * 8;
            float f[8] = {};
            if (l >= 0 && l < LDIM) {
                short8 v = *(const short8*)((const __hip_bfloat16*)in +
                                            ((size_t)b * C + c0 + r) * LDIM + l);
                #pragma unroll
                for (int k = 0; k < 8; ++k) f[k] = bf2f((unsigned short)v[k]);
            }
            #pragma unroll
            for (int k = 0; k < 8; ++k) xs[r][j8 * 8 + k] = f[k];
        }
    }
    __syncthreads();

    if constexpr (XOUT) {     // fused x -> bf16 transposed (xs still raw here)
        for (int idx = tid; idx < 512; idx += 256) {
            int row = idx >> 1, hh = idx & 1;
            short8 v;
            #pragma unroll
            for (int k = 0; k < 8; ++k) {
                __hip_bfloat16 t = __float2bfloat16(xs[hh * 8 + k][row + 64]);
                v[k] = *(short*)&t;
            }
            *(short8*)&xout[((size_t)b * PDIM + l0 + row + 1) * 256 + c0 + hh * 8] = v;
            if (l0 == 0 && row == 1)
                *(short8*)&xout[((size_t)b * PDIM) * 256 + c0 + hh * 8] = v;
            if (l0 == LDIM - 256 && row == 254)
                *(short8*)&xout[((size_t)b * PDIM + LDIM + 1) * 256 + c0 + hh * 8] = v;
        }
    }

    // means for mj in [0,292): l = l0-18+mj; numerator unmasked, denom masked
    int mstart = sub * 19;
    int mend = min(mstart + 19, 292);
    float S = 0.f;
    for (int k = 0; k <= 36; ++k) S += xs[c][mstart + k + 28];
    for (int mj = mstart; mj < mend; ++mj) {
        if (mj > mstart) S += xs[c][mj + 64] - xs[c][mj + 27];
        int l = l0 - 18 + mj;
        int lo = max(l - 18, 0), hi = min(l + 19, len);
        ms[c][mj] = (l >= 0 && l < len)
                  ? S * __builtin_amdgcn_rcpf((float)(hi - lo)) : 0.f;
    }
    __syncthreads();

    float dwn[16];
    int lbase = l0 + sub * 16;
    #pragma unroll
    for (int t = 0; t < 16; ++t)
        dwn[t] = xs[c][sub * 16 + t + 64] - ms[c][sub * 16 + t + 18];
    __syncthreads();

    // sq in place over xs
    for (int mj = mstart; mj < mend; ++mj) {
        int l = l0 - 18 + mj;
        float d = xs[c][mj + 46] - ms[c][mj];
        xs[c][mj + 46] = (l >= 0 && l < len) ? d * d : 0.f;
    }
    __syncthreads();

    float gamma = h[(size_t)b * 2 * C + c0 + c];
    float beta  = h[(size_t)b * 2 * C + C + c0 + c];
    float S2 = 0.f;
    for (int k = 0; k <= 36; ++k) S2 += xs[c][sub * 16 + 46 + k];
    #pragma unroll
    for (int t = 0; t < 16; ++t) {
        int l = lbase + t;
        if (t) S2 += xs[c][sub * 16 + t + 82] - xs[c][sub * 16 + t + 45];
        int lo = max(l - 18, 0), hi = min(l + 19, len);
        float var = (l < len) ? S2 * __builtin_amdgcn_rcpf((float)(hi - lo)) : 0.f;
        float xn = dwn[t] * __builtin_amdgcn_rsqf(var + EPSF);
        float v = fmaf(gamma, xn, xn) + beta;
        v = v > 0.f ? v : 0.2f * v;
        os[sub * 16 + t][c] = __float2bfloat16(v);
    }
    __syncthreads();

    for (int idx = tid; idx < 512; idx += 256) {
        int row = idx >> 1, hh = idx & 1;
        short8 v = *(const short8*)&os[row][hh * 8];
        *(short8*)&out[((size_t)b * PDIM + l0 + row + 1) * C + c0 + hh * 8] = v;
        if (l0 == 0 && row == 1)
            *(short8*)&out[((size_t)b * PDIM) * C + c0 + hh * 8] = v;
        if (l0 == LDIM - 256 && row == 254)
            *(short8*)&out[((size_t)b * PDIM + LDIM + 1) * C + c0 + hh * 8] = v;
    }
}

// ---------------- weight prep ----------------
// [O][I][3] f32 -> [O][3][I] bf16
__global__ void wp3_kernel(const float* __restrict__ in, __hip_bfloat16* __restrict__ o,
                           int I, int total) {
    int idx = blockIdx.x * 256 + threadIdx.x;
    if (idx >= total) return;
    int t = idx % 3;
    int rest = idx / 3;
    int i = rest % I;
    int oo = rest / I;
    o[((size_t)oo * 3 + t) * I + i] = __float2bfloat16(in[idx]);
}

__global__ void wcvt_kernel(const float* __restrict__ in, __hip_bfloat16* __restrict__ o, int total) {
    int idx = blockIdx.x * 256 + threadIdx.x;
    if (idx < total) o[idx] = __float2bfloat16(in[idx]);
}

// ---------------- conv1d(k=3, reflect) as MFMA implicit GEMM ----------------
// EXACT round-3/5/7 structure (proven: 250us conv2, VGPR 64, 0 bank conflicts,
// occupancy 44%): 2-phase double-buffered, BK=64, XOR-swizzled LDS
// (pre-swizzled global source + same XOR on read), compiler-managed waits.
// Lessons locked in: NO weight register banking (R6/R9: spills, +60-270MB
// scratch traffic at VGPR cap 128); NO BK=128 (R8: occupancy loss + conflicts);
// NO sched_barrier fences around the K-loop (R4: serializes weight latency).
template<int CIN, bool SC, bool FINAL, typename TOUT>
__global__ __launch_bounds__(256, 4) void conv_mfma_kernel(
    const __hip_bfloat16* __restrict__ act,
    const __hip_bfloat16* __restrict__ wt,
    const float* __restrict__ bias,
    const __hip_bfloat16* __restrict__ xsc,
    const __hip_bfloat16* __restrict__ wsc,
    TOUT* __restrict__ out)
{
    constexpr int NCM = CIN / 64;                 // main K-chunks (64 ch each)
    constexpr int NCT = NCM + (SC ? 4 : 0);       // + shortcut chunks
    __shared__ alignas(16) char lds[2][16640];    // 130 rows x 128B, double buffered
    int tid = threadIdx.x;
    int lane = tid & 63;
    int w = tid >> 6, wm = w >> 1, wn = w & 1;    // 2x2 wave grid, 64x64 per wave
    int l0 = blockIdx.x * 128, o0 = blockIdx.y * 128, b = blockIdx.z;

    f32x4 acc[4][4] = {};

    auto stage = [&](int kc, char* buf) {
        const __hip_bfloat16* src;
        int cs, cb;
        if (!SC || kc < NCM) { src = act + (size_t)b * PDIM * CIN; cs = CIN; cb = kc * 64; }
        else                 { src = xsc + (size_t)b * PDIM * 256; cs = 256; cb = (kc - NCM) * 64; }
        // rows p = l0 + 0..129 (l-space l0-1..l0+128), 128B/row = 8 x 16B slots.
        // Linear LDS dest; source slot pre-XORed so the swizzled READ sees the
        // right data (both-sides involution).
        for (int u = tid; u < 1040; u += 256) {
            int row = u >> 3, s = u & 7;
            int gs = s ^ (row & 7);
            const void* g = src + (size_t)(l0 + row) * cs + cb + gs * 8;
            void* d = &buf[(size_t)(u - lane) * 16];   // wave-uniform base; lane adds 16B
            gload_lds16(g, d);
        }
    };

    stage(0, lds[0]);
    __syncthreads();

    int il = lane & 15, g = lane >> 4;

    for (int kc = 0; kc < NCT; ++kc) {
        char* cur = lds[kc & 1];
        if (kc + 1 < NCT) stage(kc + 1, lds[(kc + 1) & 1]);

        bool isSC = SC && (kc >= NCM);
        int cb = isSC ? (kc - NCM) * 64 : kc * 64;
        int t0 = isSC ? 1 : 0;
        int t1 = isSC ? 2 : 3;
        for (int t = t0; t < t1; ++t) {
            #pragma unroll
            for (int ks = 0; ks < 2; ++ks) {
                short8 af[4], bfr[4];
                if (!isSC) {
                    const __hip_bfloat16* wb = wt + ((size_t)(o0 + wm * 64 + il) * 3 + t) * CIN
                                             + cb + ks * 32 + g * 8;
                    #pragma unroll
                    for (int mm = 0; mm < 4; ++mm)
                        af[mm] = *(const short8*)(wb + (size_t)mm * 16 * 3 * CIN);
                } else {
                    const __hip_bfloat16* wb = wsc + (size_t)(o0 + wm * 64 + il) * 256
                                             + cb + ks * 32 + g * 8;
                    #pragma unroll
                    for (int mm = 0; mm < 4; ++mm)
                        af[mm] = *(const short8*)(wb + (size_t)mm * 16 * 256);
                }
                #pragma unroll
                for (int nn = 0; nn < 4; ++nn) {
                    int row = wn * 64 + nn * 16 + il + t;      // tap shift = LDS row shift
                    int slot = (ks * 4 + g) ^ (row & 7);       // read-side XOR (matches source perm)
                    bfr[nn] = *(const short8*)(cur + row * 128 + slot * 16);
                }
                #pragma unroll
                for (int mm = 0; mm < 4; ++mm)
                    #pragma unroll
                    for (int nn = 0; nn < 4; ++nn)
                        acc[mm][nn] = __builtin_amdgcn_mfma_f32_16x16x32_bf16(
                            af[mm], bfr[nn], acc[mm][nn], 0, 0, 0);
            }
        }
        __syncthreads();
    }

    const float scale = FINAL ? 0.70710678118654752440f : 1.0f;
    #pragma unroll
    for (int mm = 0; mm < 4; ++mm) {
        #pragma unroll
        for (int j = 0; j < 4; ++j) {
            int row = o0 + wm * 64 + mm * 16 + g * 4 + j;  // C/D: row=(lane>>4)*4+reg
            float bv = bias[row];
            #pragma unroll
            for (int nn = 0; nn < 4; ++nn) {
                int col = l0 + wn * 64 + nn * 16 + il;     // C/D: col=lane&15
                float v = (acc[mm][nn][j] + bv) * scale;
                if constexpr (__is_same(TOUT, float))
                    out[((size_t)b * 512 + row) * LDIM + col] = v;
                else
                    out[((size_t)b * 512 + row) * LDIM + col] = __float2bfloat16(v);
            }
        }
    }
}

extern "C" void kernel_launch(void* const* d_in, const int* in_sizes, int n_in,
                              void* d_out, int out_size, void* d_ws, size_t ws_size,
                              hipStream_t stream) {
    const float* x    = (const float*)d_in[0];
    const float* s    = (const float*)d_in[1];
    const int*   lens = (const int*)d_in[2];
    const float* fc1w = (const float*)d_in[3];
    const float* fc1b = (const float*)d_in[4];
    const float* fc2w = (const float*)d_in[5];
    const float* fc2b = (const float*)d_in[6];
    const float* c1w  = (const float*)d_in[7];
    const float* c1b  = (const float*)d_in[8];
    const float* c2w  = (const float*)d_in[9];
    const float* c2b  = (const float*)d_in[10];
    const float* scw  = (const float*)d_in[11];
    float* out = (float*)d_out;

    char* ws = (char*)d_ws;
    float*          sp  = (float*)(ws);
    float*          h1  = (float*)(ws + ((size_t)1 << 20));
    float*          h2  = (float*)(ws + ((size_t)2 << 20));
    __hip_bfloat16* w1t = (__hip_bfloat16*)(ws + ((size_t)3 << 20));   // 512*768*2  = 768KB
    __hip_bfloat16* w2t = (__hip_bfloat16*)(ws + ((size_t)4 << 20));   // 512*1536*2 = 1.5MB
    __hip_bfloat16* wsc = (__hip_bfloat16*)(ws + ((size_t)6 << 20));   // 512*256*2  = 256KB
    __hip_bfloat16* xbf = (__hip_bfloat16*)(ws + ((size_t)8 << 20));   // 16*4098*256*2 = 33.6MB
    __hip_bfloat16* a1t = (__hip_bfloat16*)(ws + ((size_t)42 << 20));  // 33.6MB
    __hip_bfloat16* a2t = (__hip_bfloat16*)(ws + ((size_t)76 << 20));  // 16*4098*512*2 = 67.1MB
    __hip_bfloat16* y1b = (__hip_bfloat16*)d_out;   // bf16 y1 staged in d_out (fully
                                                    // rewritten f32 by final conv2)

    sp_kernel<<<2048, 256, 0, stream>>>(s, lens, sp);
    fc_kernel<<<96, 256, 0, stream>>>(sp, fc1w, fc1b, fc2w, fc2b, h1, h2);
    wp3_kernel<<<(512 * 256 * 3 + 255) / 256, 256, 0, stream>>>(c1w, w1t, 256, 512 * 256 * 3);
    wp3_kernel<<<(512 * 512 * 3 + 255) / 256, 256, 0, stream>>>(c2w, w2t, 512, 512 * 512 * 3);
    wcvt_kernel<<<512, 256, 0, stream>>>(scw, wsc, 512 * 256);

    adawin_t_kernel<true, float><<<dim3(16, 16, 16), 256, 0, stream>>>(
        x, h1, lens, a1t, xbf, 256);
    conv_mfma_kernel<256, false, false, __hip_bfloat16><<<dim3(32, 4, 16), 256, 0, stream>>>(
        a1t, w1t, c1b, nullptr, nullptr, y1b);
    adawin_t_kernel<false, __hip_bfloat16><<<dim3(16, 32, 16), 256, 0, stream>>>(
        y1b, h2, lens, a2t, nullptr, 512);
    conv_mfma_kernel<512, true, true, float><<<dim3(32, 4, 16), 256, 0, stream>>>(
        a2t, w2t, c2b, xbf, wsc, out);
}

// Round 11
// 476.254 us; speedup vs baseline: 1.4916x; 1.2710x over previous
//
#include <hip/hip_runtime.h>
#include <hip/hip_bf16.h>
#include <math.h>

#define LDIM 4096
#define PDIM 4098   // 1-elem reflect pad each side
#define EPSF 1e-9f

using f32x4  = __attribute__((ext_vector_type(4))) float;
using short8 = __attribute__((ext_vector_type(8))) short;

#define AS1 __attribute__((address_space(1)))
#define AS3 __attribute__((address_space(3)))

__device__ __forceinline__ void gload_lds16(const void* g, void* l) {
    __builtin_amdgcn_global_load_lds((const AS1 unsigned int*)g,
                                     (AS3 unsigned int*)l, 16, 0, 0);
}

__device__ __forceinline__ float bf2f(unsigned short u) {
    unsigned int b = ((unsigned int)u) << 16;
    return __builtin_bit_cast(float, b);
}

// ---------------- sp = (s*mask).sum(-1)/len  ----------------
__global__ void sp_kernel(const float* __restrict__ s, const int* __restrict__ lengths,
                          float* __restrict__ sp) {
    int b = blockIdx.x >> 7;
    int d = blockIdx.x & 127;
    int len = lengths[b];
    const float* row = s + ((size_t)(b * 128 + d)) * LDIM;
    float acc = 0.f;
    int len4 = len & ~3;
    for (int l = threadIdx.x * 4; l < len4; l += 1024) {
        f32x4 v = *(const f32x4*)(row + l);
        acc += v[0] + v[1] + v[2] + v[3];
    }
    for (int l = len4 + threadIdx.x; l < len; l += 256) acc += row[l];
    for (int off = 32; off; off >>= 1) acc += __shfl_down(acc, off, 64);
    __shared__ float red[4];
    if ((threadIdx.x & 63) == 0) red[threadIdx.x >> 6] = acc;
    __syncthreads();
    if (threadIdx.x == 0)
        sp[b * 128 + d] = (red[0] + red[1] + red[2] + red[3]) / (float)len;
}

// ---------------- h1 = sp@fc1^T+b1, h2 = sp@fc2^T+b2 ----------------
__global__ void fc_kernel(const float* __restrict__ sp,
                          const float* __restrict__ w1, const float* __restrict__ b1,
                          const float* __restrict__ w2, const float* __restrict__ b2,
                          float* __restrict__ h1, float* __restrict__ h2) {
    int idx = blockIdx.x * 256 + threadIdx.x;   // 16 * 1536
    int b = idx / 1536, j = idx % 1536;
    const float* spb = sp + b * 128;
    if (j < 512) {
        const float* wr = w1 + (size_t)j * 128;
        float acc = b1[j];
        for (int d = 0; d < 128; ++d) acc = fmaf(spb[d], wr[d], acc);
        h1[b * 512 + j] = acc;
    } else {
        int j2 = j - 512;
        const float* wr = w2 + (size_t)j2 * 128;
        float acc = b2[j2];
        for (int d = 0; d < 128; ++d) acc = fmaf(spb[d], wr[d], acc);
        h2[b * 1024 + j2] = acc;
    }
}

// ---------------- AdaWin + LReLU: in [b][C][L] -> out bf16 transposed [b][PDIM][C] ----------------
// Vectorized loads (float4 / short8) over aligned span [l0-64, l0+320).
// HW approx rcp/rsq (R10: neutral perf, keep -- fewer instrs, error invisible).
// XOUT: also emit bf16 of the raw input, transposed+padded (fused xcvt).
template<bool XOUT, typename TIN>
__global__ __launch_bounds__(256) void adawin_t_kernel(const TIN* __restrict__ in,
        const float* __restrict__ h, const int* __restrict__ lengths,
        __hip_bfloat16* __restrict__ out, __hip_bfloat16* __restrict__ xout, int C) {
    __shared__ float xs[16][384];           // raw x then (x-mean)^2*mask; j=0 <-> l0-64
    __shared__ float ms[16][293];           // means, mj=0 <-> l0-18
    __shared__ __hip_bfloat16 os[256][16];  // output staging (transposed)
    int l0 = blockIdx.x * 256, c0 = blockIdx.y * 16, b = blockIdx.z;
    int tid = threadIdx.x;
    int c = tid >> 4, sub = tid & 15;
    int len = lengths[b];

    if constexpr (sizeof(TIN) == 4) {       // f32 input: 96 float4 per row
        for (int i = 0; i < 6; ++i) {
            int idx = tid + i * 256;
            int r = idx / 96, j4 = idx % 96;
            int l = l0 - 64 + j4 * 4;
            f32x4 v = {};
            if (l >= 0 && l < LDIM)
                v = *(const f32x4*)((const float*)in + ((size_t)b * C + c0 + r) * LDIM + l);
            *(f32x4*)&xs[r][j4 * 4] = v;
        }
    } else {                                // bf16 input: 48 short8 per row
        for (int i = 0; i < 3; ++i) {
            int idx = tid + i * 256;
            int r = idx / 48, j8 = idx % 48;
            int l = l0 - 64 + j8 * 8;
            float f[8] = {};
            if (l >= 0 && l < LDIM) {
                short8 v = *(const short8*)((const __hip_bfloat16*)in +
                                            ((size_t)b * C + c0 + r) * LDIM + l);
                #pragma unroll
                for (int k = 0; k < 8; ++k) f[k] = bf2f((unsigned short)v[k]);
            }
            #pragma unroll
            for (int k = 0; k < 8; ++k) xs[r][j8 * 8 + k] = f[k];
        }
    }
    __syncthreads();

    if constexpr (XOUT) {     // fused x -> bf16 transposed (xs still raw here)
        for (int idx = tid; idx < 512; idx += 256) {
            int row = idx >> 1, hh = idx & 1;
            short8 v;
            #pragma unroll
            for (int k = 0; k < 8; ++k) {
                __hip_bfloat16 t = __float2bfloat16(xs[hh * 8 + k][row + 64]);
                v[k] = *(short*)&t;
            }
            *(short8*)&xout[((size_t)b * PDIM + l0 + row + 1) * 256 + c0 + hh * 8] = v;
            if (l0 == 0 && row == 1)
                *(short8*)&xout[((size_t)b * PDIM) * 256 + c0 + hh * 8] = v;
            if (l0 == LDIM - 256 && row == 254)
                *(short8*)&xout[((size_t)b * PDIM + LDIM + 1) * 256 + c0 + hh * 8] = v;
        }
    }

    // means for mj in [0,292): l = l0-18+mj; numerator unmasked, denom masked
    int mstart = sub * 19;
    int mend = min(mstart + 19, 292);
    float S = 0.f;
    for (int k = 0; k <= 36; ++k) S += xs[c][mstart + k + 28];
    for (int mj = mstart; mj < mend; ++mj) {
        if (mj > mstart) S += xs[c][mj + 64] - xs[c][mj + 27];
        int l = l0 - 18 + mj;
        int lo = max(l - 18, 0), hi = min(l + 19, len);
        ms[c][mj] = (l >= 0 && l < len)
                  ? S * __builtin_amdgcn_rcpf((float)(hi - lo)) : 0.f;
    }
    __syncthreads();

    float dwn[16];
    int lbase = l0 + sub * 16;
    #pragma unroll
    for (int t = 0; t < 16; ++t)
        dwn[t] = xs[c][sub * 16 + t + 64] - ms[c][sub * 16 + t + 18];
    __syncthreads();

    // sq in place over xs
    for (int mj = mstart; mj < mend; ++mj) {
        int l = l0 - 18 + mj;
        float d = xs[c][mj + 46] - ms[c][mj];
        xs[c][mj + 46] = (l >= 0 && l < len) ? d * d : 0.f;
    }
    __syncthreads();

    float gamma = h[(size_t)b * 2 * C + c0 + c];
    float beta  = h[(size_t)b * 2 * C + C + c0 + c];
    float S2 = 0.f;
    for (int k = 0; k <= 36; ++k) S2 += xs[c][sub * 16 + 46 + k];
    #pragma unroll
    for (int t = 0; t < 16; ++t) {
        int l = lbase + t;
        if (t) S2 += xs[c][sub * 16 + t + 82] - xs[c][sub * 16 + t + 45];
        int lo = max(l - 18, 0), hi = min(l + 19, len);
        float var = (l < len) ? S2 * __builtin_amdgcn_rcpf((float)(hi - lo)) : 0.f;
        float xn = dwn[t] * __builtin_amdgcn_rsqf(var + EPSF);
        float v = fmaf(gamma, xn, xn) + beta;
        v = v > 0.f ? v : 0.2f * v;
        os[sub * 16 + t][c] = __float2bfloat16(v);
    }
    __syncthreads();

    for (int idx = tid; idx < 512; idx += 256) {
        int row = idx >> 1, hh = idx & 1;
        short8 v = *(const short8*)&os[row][hh * 8];
        *(short8*)&out[((size_t)b * PDIM + l0 + row + 1) * C + c0 + hh * 8] = v;
        if (l0 == 0 && row == 1)
            *(short8*)&out[((size_t)b * PDIM) * C + c0 + hh * 8] = v;
        if (l0 == LDIM - 256 && row == 254)
            *(short8*)&out[((size_t)b * PDIM + LDIM + 1) * C + c0 + hh * 8] = v;
    }
}

// ---------------- weight prep ----------------
// [O][I][3] f32 -> [O][3][I] bf16
__global__ void wp3_kernel(const float* __restrict__ in, __hip_bfloat16* __restrict__ o,
                           int I, int total) {
    int idx = blockIdx.x * 256 + threadIdx.x;
    if (idx >= total) return;
    int t = idx % 3;
    int rest = idx / 3;
    int i = rest % I;
    int oo = rest / I;
    o[((size_t)oo * 3 + t) * I + i] = __float2bfloat16(in[idx]);
}

__global__ void wcvt_kernel(const float* __restrict__ in, __hip_bfloat16* __restrict__ o, int total) {
    int idx = blockIdx.x * 256 + threadIdx.x;
    if (idx < total) o[idx] = __float2bfloat16(in[idx]);
}

// ---------------- conv1d(k=3, reflect) as MFMA implicit GEMM ----------------
// Round-11: m97-invariant K-loop -- BOTH operands (weights AND activations)
// staged via global_load_lds; ZERO per-lane global loads in the loop. The
// previous structure's per-chunk weight loads forced in-order-vmcnt drains of
// the stage at every chunk (the 20%-MfmaUtil cap; reg-bank escapes spilled,
// R6/R9). BK=32 so the weight tile fits: per buffer act [130][64B] (8.3KB) +
// wt [3][128][64B] (24.6KB) = 32.9KB, double-buffered 65.8KB -> 2 blocks/CU.
// 64B rows = 4 x 16B slots; XOR involution slot = g ^ ((row>>1)&3) on BOTH
// global source and LDS read -> 2-way max bank aliasing (free, m136).
template<int CIN, bool SC, bool FINAL, typename TOUT>
__global__ __launch_bounds__(256, 2) void conv_mfma_kernel(
    const __hip_bfloat16* __restrict__ act,
    const __hip_bfloat16* __restrict__ wt,
    const float* __restrict__ bias,
    const __hip_bfloat16* __restrict__ xsc,
    const __hip_bfloat16* __restrict__ wsc,
    TOUT* __restrict__ out)
{
    constexpr int NCM = CIN / 32;                 // main K-chunks (32 ch each)
    constexpr int NCT = NCM + (SC ? 8 : 0);       // + shortcut chunks
    constexpr int ACT_SZ = 130 * 64;              // 8320
    constexpr int WT_SZ  = 3 * 128 * 64;          // 24576
    constexpr int BUFSZ  = ACT_SZ + WT_SZ;        // 32896
    __shared__ alignas(16) char lds[2][BUFSZ];
    int tid = threadIdx.x;
    int lane = tid & 63;
    int w = tid >> 6, wm = w >> 1, wn = w & 1;    // 2x2 wave grid, 64x64 per wave
    int l0 = blockIdx.x * 128, o0 = blockIdx.y * 128, b = blockIdx.z;

    f32x4 acc[4][4] = {};

    auto stage = [&](int kc, char* buf) {
        bool isSC = SC && (kc >= NCM);
        const __hip_bfloat16* asrc;
        int cs, cb;
        if (!isSC) { asrc = act + (size_t)b * PDIM * CIN; cs = CIN; cb = kc * 32; }
        else       { asrc = xsc + (size_t)b * PDIM * 256; cs = 256; cb = (kc - NCM) * 32; }
        // act tile: rows l0-1..l0+128, 64B/row = 4 slots; slot u holds channel
        // group u ^ ((row>>1)&3)  (involution matched by the read)
        for (int u = tid; u < 520; u += 256) {
            int row = u >> 2, s = u & 3;
            int gs = s ^ ((row >> 1) & 3);
            gload_lds16(asrc + (size_t)(l0 + row) * cs + cb + gs * 8,
                        buf + (size_t)(u - lane) * 16);
        }
        // weight tile: [t][row 0..127][4 slots], same per-row involution
        int nwt = isSC ? 512 : 1536;              // SC: 1 tap only
        for (int u = tid; u < nwt; u += 256) {
            int t = u >> 9;
            int rw = (u >> 2) & 127;
            int s = u & 3;
            int gs = s ^ ((rw >> 1) & 3);
            const __hip_bfloat16* wsrc;
            if (!isSC) wsrc = wt + ((size_t)(o0 + rw) * 3 + t) * CIN + kc * 32 + gs * 8;
            else       wsrc = wsc + (size_t)(o0 + rw) * 256 + (kc - NCM) * 32 + gs * 8;
            gload_lds16(wsrc, buf + ACT_SZ + (size_t)(u - lane) * 16);
        }
    };

    stage(0, lds[0]);
    __syncthreads();

    int il = lane & 15, g = lane >> 4;

    for (int kc = 0; kc < NCT; ++kc) {
        char* cur = lds[kc & 1];
        if (kc + 1 < NCT) stage(kc + 1, lds[(kc + 1) & 1]);

        bool isSC = SC && (kc >= NCM);
        int t0 = isSC ? 1 : 0;        // SC: center tap only (act row shift +1)
        int t1 = isSC ? 2 : 3;
        for (int t = t0; t < t1; ++t) {
            int wtap = isSC ? 0 : t;  // SC weights staged at tap slot 0
            short8 af[4], bfr[4];
            #pragma unroll
            for (int mm = 0; mm < 4; ++mm) {
                int row = wm * 64 + mm * 16 + il;
                int s = g ^ ((row >> 1) & 3);
                af[mm] = *(const short8*)(cur + ACT_SZ + (wtap * 128 + row) * 64 + s * 16);
            }
            #pragma unroll
            for (int nn = 0; nn < 4; ++nn) {
                int row = wn * 64 + nn * 16 + il + t;      // tap shift = LDS row shift
                int s = g ^ ((row >> 1) & 3);
                bfr[nn] = *(const short8*)(cur + row * 64 + s * 16);
            }
            #pragma unroll
            for (int mm = 0; mm < 4; ++mm)
                #pragma unroll
                for (int nn = 0; nn < 4; ++nn)
                    acc[mm][nn] = __builtin_amdgcn_mfma_f32_16x16x32_bf16(
                        af[mm], bfr[nn], acc[mm][nn], 0, 0, 0);
        }
        __syncthreads();
    }

    const float scale = FINAL ? 0.70710678118654752440f : 1.0f;
    #pragma unroll
    for (int mm = 0; mm < 4; ++mm) {
        #pragma unroll
        for (int j = 0; j < 4; ++j) {
            int row = o0 + wm * 64 + mm * 16 + g * 4 + j;  // C/D: row=(lane>>4)*4+reg
            float bv = bias[row];
            #pragma unroll
            for (int nn = 0; nn < 4; ++nn) {
                int col = l0 + wn * 64 + nn * 16 + il;     // C/D: col=lane&15
                float v = (acc[mm][nn][j] + bv) * scale;
                if constexpr (__is_same(TOUT, float))
                    out[((size_t)b * 512 + row) * LDIM + col] = v;
                else
                    out[((size_t)b * 512 + row) * LDIM + col] = __float2bfloat16(v);
            }
        }
    }
}

extern "C" void kernel_launch(void* const* d_in, const int* in_sizes, int n_in,
                              void* d_out, int out_size, void* d_ws, size_t ws_size,
                              hipStream_t stream) {
    const float* x    = (const float*)d_in[0];
    const float* s    = (const float*)d_in[1];
    const int*   lens = (const int*)d_in[2];
    const float* fc1w = (const float*)d_in[3];
    const float* fc1b = (const float*)d_in[4];
    const float* fc2w = (const float*)d_in[5];
    const float* fc2b = (const float*)d_in[6];
    const float* c1w  = (const float*)d_in[7];
    const float* c1b  = (const float*)d_in[8];
    const float* c2w  = (const float*)d_in[9];
    const float* c2b  = (const float*)d_in[10];
    const float* scw  = (const float*)d_in[11];
    float* out = (float*)d_out;

    char* ws = (char*)d_ws;
    float*          sp  = (float*)(ws);
    float*          h1  = (float*)(ws + ((size_t)1 << 20));
    float*          h2  = (float*)(ws + ((size_t)2 << 20));
    __hip_bfloat16* w1t = (__hip_bfloat16*)(ws + ((size_t)3 << 20));   // 512*768*2  = 768KB
    __hip_bfloat16* w2t = (__hip_bfloat16*)(ws + ((size_t)4 << 20));   // 512*1536*2 = 1.5MB
    __hip_bfloat16* wsc = (__hip_bfloat16*)(ws + ((size_t)6 << 20));   // 512*256*2  = 256KB
    __hip_bfloat16* xbf = (__hip_bfloat16*)(ws + ((size_t)8 << 20));   // 16*4098*256*2 = 33.6MB
    __hip_bfloat16* a1t = (__hip_bfloat16*)(ws + ((size_t)42 << 20));  // 33.6MB
    __hip_bfloat16* a2t = (__hip_bfloat16*)(ws + ((size_t)76 << 20));  // 16*4098*512*2 = 67.1MB
    __hip_bfloat16* y1b = (__hip_bfloat16*)d_out;   // bf16 y1 staged in d_out (fully
                                                    // rewritten f32 by final conv2)

    sp_kernel<<<2048, 256, 0, stream>>>(s, lens, sp);
    fc_kernel<<<96, 256, 0, stream>>>(sp, fc1w, fc1b, fc2w, fc2b, h1, h2);
    wp3_kernel<<<(512 * 256 * 3 + 255) / 256, 256, 0, stream>>>(c1w, w1t, 256, 512 * 256 * 3);
    wp3_kernel<<<(512 * 512 * 3 + 255) / 256, 256, 0, stream>>>(c2w, w2t, 512, 512 * 512 * 3);
    wcvt_kernel<<<512, 256, 0, stream>>>(scw, wsc, 512 * 256);

    adawin_t_kernel<true, float><<<dim3(16, 16, 16), 256, 0, stream>>>(
        x, h1, lens, a1t, xbf, 256);
    conv_mfma_kernel<256, false, false, __hip_bfloat16><<<dim3(32, 4, 16), 256, 0, stream>>>(
        a1t, w1t, c1b, nullptr, nullptr, y1b);
    adawin_t_kernel<false, __hip_bfloat16><<<dim3(16, 32, 16), 256, 0, stream>>>(
        y1b, h2, lens, a2t, nullptr, 512);
    conv_mfma_kernel<512, true, true, float><<<dim3(32, 4, 16), 256, 0, stream>>>(
        a2t, w2t, c2b, xbf, wsc, out);
}

// Round 12
// 426.003 us; speedup vs baseline: 1.6675x; 1.1180x over previous
//
#include <hip/hip_runtime.h>
#include <hip/hip_bf16.h>
#include <math.h>

#define LDIM 4096
#define PDIM 4098   // 1-elem reflect pad each side
#define EPSF 1e-9f

using f32x4  = __attribute__((ext_vector_type(4))) float;
using short8 = __attribute__((ext_vector_type(8))) short;

#define AS1 __attribute__((address_space(1)))
#define AS3 __attribute__((address_space(3)))

__device__ __forceinline__ void gload_lds16(const void* g, void* l) {
    __builtin_amdgcn_global_load_lds((const AS1 unsigned int*)g,
                                     (AS3 unsigned int*)l, 16, 0, 0);
}

__device__ __forceinline__ float bf2f(unsigned short u) {
    unsigned int b = ((unsigned int)u) << 16;
    return __builtin_bit_cast(float, b);
}

// ---------------- sp = (s*mask).sum(-1)/len  ----------------
__global__ void sp_kernel(const float* __restrict__ s, const int* __restrict__ lengths,
                          float* __restrict__ sp) {
    int b = blockIdx.x >> 7;
    int d = blockIdx.x & 127;
    int len = lengths[b];
    const float* row = s + ((size_t)(b * 128 + d)) * LDIM;
    float acc = 0.f;
    int len4 = len & ~3;
    for (int l = threadIdx.x * 4; l < len4; l += 1024) {
        f32x4 v = *(const f32x4*)(row + l);
        acc += v[0] + v[1] + v[2] + v[3];
    }
    for (int l = len4 + threadIdx.x; l < len; l += 256) acc += row[l];
    for (int off = 32; off; off >>= 1) acc += __shfl_down(acc, off, 64);
    __shared__ float red[4];
    if ((threadIdx.x & 63) == 0) red[threadIdx.x >> 6] = acc;
    __syncthreads();
    if (threadIdx.x == 0)
        sp[b * 128 + d] = (red[0] + red[1] + red[2] + red[3]) / (float)len;
}

// ---------------- h1 = sp@fc1^T+b1, h2 = sp@fc2^T+b2 ----------------
__global__ void fc_kernel(const float* __restrict__ sp,
                          const float* __restrict__ w1, const float* __restrict__ b1,
                          const float* __restrict__ w2, const float* __restrict__ b2,
                          float* __restrict__ h1, float* __restrict__ h2) {
    int idx = blockIdx.x * 256 + threadIdx.x;   // 16 * 1536
    int b = idx / 1536, j = idx % 1536;
    const float* spb = sp + b * 128;
    if (j < 512) {
        const float* wr = w1 + (size_t)j * 128;
        float acc = b1[j];
        for (int d = 0; d < 128; ++d) acc = fmaf(spb[d], wr[d], acc);
        h1[b * 512 + j] = acc;
    } else {
        int j2 = j - 512;
        const float* wr = w2 + (size_t)j2 * 128;
        float acc = b2[j2];
        for (int d = 0; d < 128; ++d) acc = fmaf(spb[d], wr[d], acc);
        h2[b * 1024 + j2] = acc;
    }
}

// ---------------- AdaWin + LReLU: in [b][C][L] -> out bf16 transposed [b][PDIM][C] ----------------
// Round-12 rework of the middle section:
//  - sq (squared deviations) kept in a 52-register array (static indices) --
//    removes the in-place xs rewrite and 2 of 5 barriers.
//  - means stored bf16 (9.4KB vs 18.8) -- absmax driver (l>=len) has ms==0
//    exactly; in-range mean quantization ~0.4% rel, far under threshold.
//  - xs tightened to [16][352], span [l0-48, l0+304), vector-aligned.
//  LDS 39.2KB -> 4 blocks/CU (was 3); barriers 5 -> 3.
// XOUT: also emit bf16 of the raw input, transposed+padded (fused xcvt).
template<bool XOUT, typename TIN>
__global__ __launch_bounds__(256) void adawin_t_kernel(const TIN* __restrict__ in,
        const float* __restrict__ h, const int* __restrict__ lengths,
        __hip_bfloat16* __restrict__ out, __hip_bfloat16* __restrict__ xout, int C) {
    __shared__ float xs[16][352];            // raw x; j=0 <-> l0-48
    __shared__ __hip_bfloat16 msb[16][294];  // means (bf16), mj=0 <-> l0-18
    __shared__ __hip_bfloat16 os[256][16];   // output staging (transposed)
    int l0 = blockIdx.x * 256, c0 = blockIdx.y * 16, b = blockIdx.z;
    int tid = threadIdx.x;
    int c = tid >> 4, sub = tid & 15;
    int len = lengths[b];

    if constexpr (sizeof(TIN) == 4) {       // f32 input: 88 float4 per row
        for (int i = 0; i < 6; ++i) {
            int idx = tid + i * 256;
            if (idx < 16 * 88) {
                int r = idx / 88, j4 = idx % 88;
                int l = l0 - 48 + j4 * 4;
                f32x4 v = {};
                if (l >= 0 && l < LDIM)
                    v = *(const f32x4*)((const float*)in + ((size_t)b * C + c0 + r) * LDIM + l);
                *(f32x4*)&xs[r][j4 * 4] = v;
            }
        }
    } else {                                // bf16 input: 44 short8 per row
        for (int i = 0; i < 3; ++i) {
            int idx = tid + i * 256;
            if (idx < 16 * 44) {
                int r = idx / 44, j8 = idx % 44;
                int l = l0 - 48 + j8 * 8;
                float f[8] = {};
                if (l >= 0 && l < LDIM) {
                    short8 v = *(const short8*)((const __hip_bfloat16*)in +
                                                ((size_t)b * C + c0 + r) * LDIM + l);
                    #pragma unroll
                    for (int k = 0; k < 8; ++k) f[k] = bf2f((unsigned short)v[k]);
                }
                #pragma unroll
                for (int k = 0; k < 8; ++k) xs[r][j8 * 8 + k] = f[k];
            }
        }
    }
    __syncthreads();

    if constexpr (XOUT) {     // fused x -> bf16 transposed (xs is read-only now)
        for (int idx = tid; idx < 512; idx += 256) {
            int row = idx >> 1, hh = idx & 1;
            short8 v;
            #pragma unroll
            for (int k = 0; k < 8; ++k) {
                __hip_bfloat16 t = __float2bfloat16(xs[hh * 8 + k][row + 48]);
                v[k] = *(short*)&t;
            }
            *(short8*)&xout[((size_t)b * PDIM + l0 + row + 1) * 256 + c0 + hh * 8] = v;
            if (l0 == 0 && row == 1)
                *(short8*)&xout[((size_t)b * PDIM) * 256 + c0 + hh * 8] = v;
            if (l0 == LDIM - 256 && row == 254)
                *(short8*)&xout[((size_t)b * PDIM + LDIM + 1) * 256 + c0 + hh * 8] = v;
        }
    }

    // cooperative means for mj in [0,292): l = l0-18+mj
    // window x-idx range [mj+12, mj+48]; numerator unmasked, denom masked
    int mstart = sub * 19;
    int mend = min(mstart + 19, 292);
    float S = 0.f;
    for (int k = 0; k <= 36; ++k) S += xs[c][mstart + k + 12];
    for (int mj = mstart; mj < mend; ++mj) {
        if (mj > mstart) S += xs[c][mj + 48] - xs[c][mj + 11];
        int l = l0 - 18 + mj;
        int lo = max(l - 18, 0), hi = min(l + 19, len);
        float mval = (l >= 0 && l < len)
                   ? S * __builtin_amdgcn_rcpf((float)(hi - lo)) : 0.f;
        msb[c][mj] = __float2bfloat16(mval);
    }
    __syncthreads();

    // register-local: sq[52] covers j in [p-18, p+33], p = l0 + sub*16
    float gamma = h[(size_t)b * 2 * C + c0 + c];
    float beta  = h[(size_t)b * 2 * C + C + c0 + c];
    int lbase = l0 + sub * 16;
    float sq[52], dwn[16];
    #pragma unroll
    for (int k = 0; k < 52; ++k) {
        int j = lbase - 18 + k;
        float d = xs[c][sub * 16 + k + 30] - __bfloat162float(msb[c][sub * 16 + k]);
        if (k >= 18 && k < 34) dwn[k - 18] = d;
        sq[k] = (j >= 0 && j < len) ? d * d : 0.f;
    }
    float S2 = 0.f;
    #pragma unroll
    for (int k = 0; k <= 36; ++k) S2 += sq[k];
    #pragma unroll
    for (int t = 0; t < 16; ++t) {
        int l = lbase + t;
        if (t) S2 += sq[t + 36] - sq[t - 1];
        int lo = max(l - 18, 0), hi = min(l + 19, len);
        float var = (l < len) ? S2 * __builtin_amdgcn_rcpf((float)(hi - lo)) : 0.f;
        float xn = dwn[t] * __builtin_amdgcn_rsqf(var + EPSF);
        float v = fmaf(gamma, xn, xn) + beta;
        v = v > 0.f ? v : 0.2f * v;
        os[sub * 16 + t][c] = __float2bfloat16(v);
    }
    __syncthreads();

    for (int idx = tid; idx < 512; idx += 256) {
        int row = idx >> 1, hh = idx & 1;
        short8 v = *(const short8*)&os[row][hh * 8];
        *(short8*)&out[((size_t)b * PDIM + l0 + row + 1) * C + c0 + hh * 8] = v;
        if (l0 == 0 && row == 1)
            *(short8*)&out[((size_t)b * PDIM) * C + c0 + hh * 8] = v;
        if (l0 == LDIM - 256 && row == 254)
            *(short8*)&out[((size_t)b * PDIM + LDIM + 1) * C + c0 + hh * 8] = v;
    }
}

// ---------------- weight prep ----------------
// [O][I][3] f32 -> [O][3][I] bf16
__global__ void wp3_kernel(const float* __restrict__ in, __hip_bfloat16* __restrict__ o,
                           int I, int total) {
    int idx = blockIdx.x * 256 + threadIdx.x;
    if (idx >= total) return;
    int t = idx % 3;
    int rest = idx / 3;
    int i = rest % I;
    int oo = rest / I;
    o[((size_t)oo * 3 + t) * I + i] = __float2bfloat16(in[idx]);
}

__global__ void wcvt_kernel(const float* __restrict__ in, __hip_bfloat16* __restrict__ o, int total) {
    int idx = blockIdx.x * 256 + threadIdx.x;
    if (idx < total) o[idx] = __float2bfloat16(in[idx]);
}

// ---------------- conv1d(k=3, reflect) as MFMA implicit GEMM ----------------
// Round-11 WINNER (conv2 171us, MfmaUtil 30.6%, 0 conflicts): m97-invariant
// K-loop -- BOTH operands staged via global_load_lds; ZERO per-lane global
// loads in the loop (per-chunk weight loads forced in-order-vmcnt drains of
// the stage; reg-bank escapes spilled, R6/R9). BK=32: per buffer act
// [130][64B] (8.3KB) + wt [3][128][64B] (24.6KB) = 32.9KB, dbuf 65.8KB ->
// 2 blocks/CU. 64B rows = 4 x 16B slots; XOR involution slot = g^((row>>1)&3)
// on BOTH global source and LDS read -> 2-way max bank aliasing (free, m136).
template<int CIN, bool SC, bool FINAL, typename TOUT>
__global__ __launch_bounds__(256, 2) void conv_mfma_kernel(
    const __hip_bfloat16* __restrict__ act,
    const __hip_bfloat16* __restrict__ wt,
    const float* __restrict__ bias,
    const __hip_bfloat16* __restrict__ xsc,
    const __hip_bfloat16* __restrict__ wsc,
    TOUT* __restrict__ out)
{
    constexpr int NCM = CIN / 32;                 // main K-chunks (32 ch each)
    constexpr int NCT = NCM + (SC ? 8 : 0);       // + shortcut chunks
    constexpr int ACT_SZ = 130 * 64;              // 8320
    constexpr int WT_SZ  = 3 * 128 * 64;          // 24576
    constexpr int BUFSZ  = ACT_SZ + WT_SZ;        // 32896
    __shared__ alignas(16) char lds[2][BUFSZ];
    int tid = threadIdx.x;
    int lane = tid & 63;
    int w = tid >> 6, wm = w >> 1, wn = w & 1;    // 2x2 wave grid, 64x64 per wave
    int l0 = blockIdx.x * 128, o0 = blockIdx.y * 128, b = blockIdx.z;

    f32x4 acc[4][4] = {};

    auto stage = [&](int kc, char* buf) {
        bool isSC = SC && (kc >= NCM);
        const __hip_bfloat16* asrc;
        int cs, cb;
        if (!isSC) { asrc = act + (size_t)b * PDIM * CIN; cs = CIN; cb = kc * 32; }
        else       { asrc = xsc + (size_t)b * PDIM * 256; cs = 256; cb = (kc - NCM) * 32; }
        // act tile: rows l0-1..l0+128, 64B/row = 4 slots; slot u holds channel
        // group u ^ ((row>>1)&3)  (involution matched by the read)
        for (int u = tid; u < 520; u += 256) {
            int row = u >> 2, s = u & 3;
            int gs = s ^ ((row >> 1) & 3);
            gload_lds16(asrc + (size_t)(l0 + row) * cs + cb + gs * 8,
                        buf + (size_t)(u - lane) * 16);
        }
        // weight tile: [t][row 0..127][4 slots], same per-row involution
        int nwt = isSC ? 512 : 1536;              // SC: 1 tap only
        for (int u = tid; u < nwt; u += 256) {
            int t = u >> 9;
            int rw = (u >> 2) & 127;
            int s = u & 3;
            int gs = s ^ ((rw >> 1) & 3);
            const __hip_bfloat16* wsrc;
            if (!isSC) wsrc = wt + ((size_t)(o0 + rw) * 3 + t) * CIN + kc * 32 + gs * 8;
            else       wsrc = wsc + (size_t)(o0 + rw) * 256 + (kc - NCM) * 32 + gs * 8;
            gload_lds16(wsrc, buf + ACT_SZ + (size_t)(u - lane) * 16);
        }
    };

    stage(0, lds[0]);
    __syncthreads();

    int il = lane & 15, g = lane >> 4;

    for (int kc = 0; kc < NCT; ++kc) {
        char* cur = lds[kc & 1];
        if (kc + 1 < NCT) stage(kc + 1, lds[(kc + 1) & 1]);

        bool isSC = SC && (kc >= NCM);
        int t0 = isSC ? 1 : 0;        // SC: center tap only (act row shift +1)
        int t1 = isSC ? 2 : 3;
        for (int t = t0; t < t1; ++t) {
            int wtap = isSC ? 0 : t;  // SC weights staged at tap slot 0
            short8 af[4], bfr[4];
            #pragma unroll
            for (int mm = 0; mm < 4; ++mm) {
                int row = wm * 64 + mm * 16 + il;
                int s = g ^ ((row >> 1) & 3);
                af[mm] = *(const short8*)(cur + ACT_SZ + (wtap * 128 + row) * 64 + s * 16);
            }
            #pragma unroll
            for (int nn = 0; nn < 4; ++nn) {
                int row = wn * 64 + nn * 16 + il + t;      // tap shift = LDS row shift
                int s = g ^ ((row >> 1) & 3);
                bfr[nn] = *(const short8*)(cur + row * 64 + s * 16);
            }
            #pragma unroll
            for (int mm = 0; mm < 4; ++mm)
                #pragma unroll
                for (int nn = 0; nn < 4; ++nn)
                    acc[mm][nn] = __builtin_amdgcn_mfma_f32_16x16x32_bf16(
                        af[mm], bfr[nn], acc[mm][nn], 0, 0, 0);
        }
        __syncthreads();
    }

    const float scale = FINAL ? 0.70710678118654752440f : 1.0f;
    #pragma unroll
    for (int mm = 0; mm < 4; ++mm) {
        #pragma unroll
        for (int j = 0; j < 4; ++j) {
            int row = o0 + wm * 64 + mm * 16 + g * 4 + j;  // C/D: row=(lane>>4)*4+reg
            float bv = bias[row];
            #pragma unroll
            for (int nn = 0; nn < 4; ++nn) {
                int col = l0 + wn * 64 + nn * 16 + il;     // C/D: col=lane&15
                float v = (acc[mm][nn][j] + bv) * scale;
                if constexpr (__is_same(TOUT, float))
                    out[((size_t)b * 512 + row) * LDIM + col] = v;
                else
                    out[((size_t)b * 512 + row) * LDIM + col] = __float2bfloat16(v);
            }
        }
    }
}

extern "C" void kernel_launch(void* const* d_in, const int* in_sizes, int n_in,
                              void* d_out, int out_size, void* d_ws, size_t ws_size,
                              hipStream_t stream) {
    const float* x    = (const float*)d_in[0];
    const float* s    = (const float*)d_in[1];
    const int*   lens = (const int*)d_in[2];
    const float* fc1w = (const float*)d_in[3];
    const float* fc1b = (const float*)d_in[4];
    const float* fc2w = (const float*)d_in[5];
    const float* fc2b = (const float*)d_in[6];
    const float* c1w  = (const float*)d_in[7];
    const float* c1b  = (const float*)d_in[8];
    const float* c2w  = (const float*)d_in[9];
    const float* c2b  = (const float*)d_in[10];
    const float* scw  = (const float*)d_in[11];
    float* out = (float*)d_out;

    char* ws = (char*)d_ws;
    float*          sp  = (float*)(ws);
    float*          h1  = (float*)(ws + ((size_t)1 << 20));
    float*          h2  = (float*)(ws + ((size_t)2 << 20));
    __hip_bfloat16* w1t = (__hip_bfloat16*)(ws + ((size_t)3 << 20));   // 512*768*2  = 768KB
    __hip_bfloat16* w2t = (__hip_bfloat16*)(ws + ((size_t)4 << 20));   // 512*1536*2 = 1.5MB
    __hip_bfloat16* wsc = (__hip_bfloat16*)(ws + ((size_t)6 << 20));   // 512*256*2  = 256KB
    __hip_bfloat16* xbf = (__hip_bfloat16*)(ws + ((size_t)8 << 20));   // 16*4098*256*2 = 33.6MB
    __hip_bfloat16* a1t = (__hip_bfloat16*)(ws + ((size_t)42 << 20));  // 33.6MB
    __hip_bfloat16* a2t = (__hip_bfloat16*)(ws + ((size_t)76 << 20));  // 16*4098*512*2 = 67.1MB
    __hip_bfloat16* y1b = (__hip_bfloat16*)d_out;   // bf16 y1 staged in d_out (fully
                                                    // rewritten f32 by final conv2)

    sp_kernel<<<2048, 256, 0, stream>>>(s, lens, sp);
    fc_kernel<<<96, 256, 0, stream>>>(sp, fc1w, fc1b, fc2w, fc2b, h1, h2);
    wp3_kernel<<<(512 * 256 * 3 + 255) / 256, 256, 0, stream>>>(c1w, w1t, 256, 512 * 256 * 3);
    wp3_kernel<<<(512 * 512 * 3 + 255) / 256, 256, 0, stream>>>(c2w, w2t, 512, 512 * 512 * 3);
    wcvt_kernel<<<512, 256, 0, stream>>>(scw, wsc, 512 * 256);

    adawin_t_kernel<true, float><<<dim3(16, 16, 16), 256, 0, stream>>>(
        x, h1, lens, a1t, xbf, 256);
    conv_mfma_kernel<256, false, false, __hip_bfloat16><<<dim3(32, 4, 16), 256, 0, stream>>>(
        a1t, w1t, c1b, nullptr, nullptr, y1b);
    adawin_t_kernel<false, __hip_bfloat16><<<dim3(16, 32, 16), 256, 0, stream>>>(
        y1b, h2, lens, a2t, nullptr, 512);
    conv_mfma_kernel<512, true, true, float><<<dim3(32, 4, 16), 256, 0, stream>>>(
        a2t, w2t, c2b, xbf, wsc, out);
}